// Round 4
// baseline (3249.151 us; speedup 1.0000x reference)
//
#include <hip/hip_runtime.h>
#include <stdint.h>

typedef _Float16 half8 __attribute__((ext_vector_type(8)));
typedef __attribute__((ext_vector_type(4))) float f32x4;

struct alignas(16) I4 { int x, y, z, w; };
struct alignas(8)  U2 { unsigned x, y; };
struct alignas(16) F4 { float x, y, z, w; };

__device__ __forceinline__ unsigned short f2h(float f) {
  return __builtin_bit_cast(unsigned short, (_Float16)f);
}
__device__ __forceinline__ float fast_tanh(float x) {
  float a = fabsf(x);
  float e = __expf(2.0f * a);
  float r = 1.0f - 2.0f / (e + 1.0f);
  return copysignf(r, x);
}

// ws layout (bytes):
//   0        : xa fp16 [S=512][B=64][H=512]            = 33,554,432
//   33554432 : W_ih fp16 [512][512]                    =    524,288
//   34078720 : W_hh fp16 [512][512]                    =    524,288
//   34603008 : hbuf fp32 [4 groups][2 parity][16][512] =    262,144
//   34865152 : flags int [4 groups][512 steps][4]      =     32,768
#define XA_OFF   0
#define WIH_OFF  33554432
#define WHH_OFF  (33554432 + 524288)
#define HBUF_OFF (33554432 + 1048576)
#define FLG_OFF  (33554432 + 1048576 + 262144)
#define YSIZE    33554432ull

// ---------------- prep: cvt weights to fp16, zero hbuf + flags -------------
__global__ __launch_bounds__(256) void prep_kernel(
    const float* __restrict__ Wih, const float* __restrict__ Whh,
    _Float16* __restrict__ WihH, _Float16* __restrict__ WhhH,
    float* __restrict__ hbuf, int* __restrict__ flg) {
  int t = blockIdx.x * 256 + threadIdx.x;  // grid = 1024*256 = 262144 exactly
  WihH[t] = (_Float16)Wih[t];
  WhhH[t] = (_Float16)Whh[t];
  if (t < 4 * 2 * 16 * 512) hbuf[t] = 0.0f;
  if (t < 4 * 512 * 4) flg[t] = 0;
}

// ---------------- gemm1: xa = x @ W_ih^T + b_ih + b_hh (fp16 MFMA) --------
#define G1S 40  // LDS row stride in fp16 elems
__global__ __launch_bounds__(256) void gemm1_kernel(
    const float* __restrict__ x, const _Float16* __restrict__ WihH,
    const float* __restrict__ bih, const float* __restrict__ bhh,
    _Float16* __restrict__ xa) {
  __shared__ alignas(16) _Float16 Alds[128 * G1S];
  const int wg = blockIdx.x;            // 1024 wgs: 256 m-tiles x 4 n-tiles
  const int nt = wg & 3, mt = wg >> 2;
  const int tid = threadIdx.x;
  const int wave = tid >> 6, lane = tid & 63;
  const int wm = wave & 1, wn = wave >> 1;
  const int l15 = lane & 15, quad = lane >> 4;

  f32x4 acc[4][4] = {};

  const int arow = tid >> 1, ahalf = tid & 1;
  const float* aptr = x + (size_t)(mt * 128 + arow) * 512 + ahalf * 16;
  _Float16* awr = Alds + arow * G1S + ahalf * 16;
  const int nbase = nt * 128 + wn * 64;

  for (int ks = 0; ks < 16; ++ks) {
    const F4* ap = (const F4*)(aptr + ks * 32);
#pragma unroll
    for (int j = 0; j < 4; ++j) {
      F4 v = ap[j];
      U2 u;
      u.x = (unsigned)f2h(v.x) | ((unsigned)f2h(v.y) << 16);
      u.y = (unsigned)f2h(v.z) | ((unsigned)f2h(v.w) << 16);
      *(U2*)(awr + j * 4) = u;
    }
    __syncthreads();

    half8 bfrag[4];
#pragma unroll
    for (int ni = 0; ni < 4; ++ni) {
      const int n = nbase + ni * 16 + l15;
      bfrag[ni] = __builtin_bit_cast(
          half8, *(const I4*)(WihH + (size_t)n * 512 + ks * 32 + quad * 8));
    }
    half8 afrag[4];
#pragma unroll
    for (int mi = 0; mi < 4; ++mi) {
      const _Float16* ard = Alds + (wm * 64 + mi * 16 + l15) * G1S + quad * 8;
      afrag[mi] = __builtin_bit_cast(half8, *(const I4*)ard);
    }
#pragma unroll
    for (int mi = 0; mi < 4; ++mi)
#pragma unroll
      for (int ni = 0; ni < 4; ++ni)
        acc[mi][ni] = __builtin_amdgcn_mfma_f32_16x16x32_f16(
            afrag[mi], bfrag[ni], acc[mi][ni], 0, 0, 0);
    __syncthreads();
  }

#pragma unroll
  for (int ni = 0; ni < 4; ++ni) {
    const int n = nbase + ni * 16 + l15;
    const float bias = bih[n] + bhh[n];
#pragma unroll
    for (int mi = 0; mi < 4; ++mi) {
#pragma unroll
      for (int r = 0; r < 4; ++r) {
        int m = mt * 128 + wm * 64 + mi * 16 + quad * 4 + r;
        int b = m >> 9, s = m & 511;
        xa[(size_t)(s * 64 + b) * 512 + n] = (_Float16)(acc[mi][ni][r] + bias);
      }
    }
  }
}

// ---------------- rnn: 512 steps; 4 groups x 4 slice-wgs (16 wgs) ---------
// Sync: relaxed agent-scope atomics ONLY (round-2-proven; NO inline-asm
// cache tricks, NO XCD discovery — round 3's hang suspects). HBM ops are
// kept out of the barrier-drain path: xa via double-buffered LDS chunks
// loaded 4 steps ahead; y stored from registers after the flag.
#define NCH 4   // steps per xa chunk
__global__ __launch_bounds__(256, 1) void rnn_kernel(
    const _Float16* __restrict__ xa, const _Float16* __restrict__ WhhH,
    float* __restrict__ hbuf, int* __restrict__ flg, float* __restrict__ out) {
  __shared__ alignas(16) _Float16 hpl[16 * 512];            // 16 KB, xor-swizzled
  __shared__ alignas(16) _Float16 xach[2][NCH * 16 * 128];  // 32 KB
  const int bid = blockIdx.x;          // 16 wgs
  const int group = bid & 3, slice = bid >> 2;
  const int tid = threadIdx.x;
  const int wave = tid >> 6, lane = tid & 63;
  const int l15 = lane & 15, quad = lane >> 4;
  const int colbase = slice * 128 + wave * 32;  // + {0,16} + l15
  const int seqbase = group * 16;

  // W_hh B-fragments resident in registers for all 512 steps (2 colsets)
  half8 bfrag[2][16];
#pragma unroll
  for (int cs = 0; cs < 2; ++cs)
#pragma unroll
    for (int kt = 0; kt < 16; ++kt)
      bfrag[cs][kt] = __builtin_bit_cast(
          half8, *(const I4*)(WhhH + (size_t)(colbase + cs * 16 + l15) * 512 +
                              kt * 32 + quad * 8));

  float* hb = hbuf + group * (2 * 8192);
  int* flg_g = flg + group * (512 * 4);

  const int srow = tid >> 4, scol = (tid & 15) * 32;  // staging assignment

  // ---- xa chunk preamble: chunk0 -> buf0 (direct), issue chunk1 -> regs ----
  I4 xreg[4];
#pragma unroll
  for (int j = 0; j < 4; ++j) {
    int slot = j * 256 + tid, s = slot >> 8, m = (slot >> 4) & 15, cb = slot & 15;
    I4 v = *(const I4*)(xa + ((size_t)s * 64 + seqbase + m) * 512 +
                        slice * 128 + cb * 8);
    *(I4*)(&xach[0][(s * 16 + m) * 128 + cb * 8]) = v;
  }
#pragma unroll
  for (int j = 0; j < 4; ++j) {
    int slot = j * 256 + tid, s = slot >> 8, m = (slot >> 4) & 15, cb = slot & 15;
    xreg[j] = *(const I4*)(xa + ((size_t)(NCH + s) * 64 + seqbase + m) * 512 +
                           slice * 128 + cb * 8);
  }
  // zero h plane (h_0 = 0)
#pragma unroll
  for (int j = 0; j < 4; ++j) {
    I4 z = {0, 0, 0, 0};
    *(I4*)(hpl + (j * 256 + tid) * 8) = z;
  }
  __syncthreads();

  for (int t = 0; t < 512; ++t) {
    if (t > 0) {
      // ---- wait for step t-1 publication from all 4 wgs ----
      const int* fp = flg_g + (t - 1) * 4 + (lane & 3);
      for (;;) {
        int v = __hip_atomic_load(fp, __ATOMIC_RELAXED, __HIP_MEMORY_SCOPE_AGENT);
        if (__all(v != 0)) break;
        __builtin_amdgcn_s_sleep(1);
      }
      // ---- stage h_t: 32 fp32 agent loads -> fp16 swizzled LDS plane ----
      const float* src = hb + (t & 1) * 8192 + srow * 512 + scol;
      float vals[32];
#pragma unroll
      for (int j = 0; j < 32; ++j)
        vals[j] = __hip_atomic_load(src + j, __ATOMIC_RELAXED,
                                    __HIP_MEMORY_SCOPE_AGENT);
      const int xr = srow & 7;
#pragma unroll
      for (int jb = 0; jb < 4; ++jb) {
        I4 pv;
        pv.x = (int)((unsigned)f2h(vals[jb * 8 + 0]) | ((unsigned)f2h(vals[jb * 8 + 1]) << 16));
        pv.y = (int)((unsigned)f2h(vals[jb * 8 + 2]) | ((unsigned)f2h(vals[jb * 8 + 3]) << 16));
        pv.z = (int)((unsigned)f2h(vals[jb * 8 + 4]) | ((unsigned)f2h(vals[jb * 8 + 5]) << 16));
        pv.w = (int)((unsigned)f2h(vals[jb * 8 + 6]) | ((unsigned)f2h(vals[jb * 8 + 7]) << 16));
        int c8 = (scol >> 3) + jb;
        *(I4*)(hpl + srow * 512 + ((c8 ^ xr) << 3)) = pv;
      }
    }
    __syncthreads();

    // ---- MFMA: 16 kt, A-frag swizzled b128 reads, 2 independent chains ----
    f32x4 acc0 = {}, acc1 = {};
    {
      const _Float16* pl = hpl + l15 * 512;
      const int xrr = l15 & 7;
#pragma unroll
      for (int kt = 0; kt < 16; ++kt) {
        half8 a = __builtin_bit_cast(
            half8, *(const I4*)(pl + (((kt * 4 + quad) ^ xrr) << 3)));
        acc0 = __builtin_amdgcn_mfma_f32_16x16x32_f16(a, bfrag[0][kt], acc0, 0, 0, 0);
        acc1 = __builtin_amdgcn_mfma_f32_16x16x32_f16(a, bfrag[1][kt], acc1, 0, 0, 0);
      }
    }

    // ---- epilogue: + xa (LDS), tanh; publish h_{t+1} (agent atomics) ----
    float* dsth = hb + ((t + 1) & 1) * 8192;
    const _Float16* xrow = &xach[(t >> 2) & 1][(t & 3) * 16 * 128];
    float hv0[4], hv1[4];
#pragma unroll
    for (int r = 0; r < 4; ++r) {
      const int m = quad * 4 + r;  // C row = sequence index
      float p0 = acc0[r] + (float)xrow[m * 128 + wave * 32 + l15];
      float p1 = acc1[r] + (float)xrow[m * 128 + wave * 32 + 16 + l15];
      hv0[r] = fast_tanh(p0);
      hv1[r] = fast_tanh(p1);
      __hip_atomic_store(dsth + m * 512 + colbase + l15, hv0[r],
                         __ATOMIC_RELAXED, __HIP_MEMORY_SCOPE_AGENT);
      __hip_atomic_store(dsth + m * 512 + colbase + 16 + l15, hv1[r],
                         __ATOMIC_RELAXED, __HIP_MEMORY_SCOPE_AGENT);
    }

    // ---- xa chunk rotation (off sync path; loads issued 4 steps early) ----
    if ((t & 3) == 2) {
      int cw = (t >> 2) + 1;
      if (cw < 128) {
#pragma unroll
        for (int j = 0; j < 4; ++j) {
          int slot = j * 256 + tid, s = slot >> 8, m = (slot >> 4) & 15, cb = slot & 15;
          *(I4*)(&xach[cw & 1][(s * 16 + m) * 128 + cb * 8]) = xreg[j];
        }
        if (cw + 1 < 128) {
          int t0 = (cw + 1) * NCH;
#pragma unroll
          for (int j = 0; j < 4; ++j) {
            int slot = j * 256 + tid, s = slot >> 8, m = (slot >> 4) & 15, cb = slot & 15;
            xreg[j] = *(const I4*)(xa + ((size_t)(t0 + s) * 64 + seqbase + m) * 512 +
                                   slice * 128 + cb * 8);
          }
        }
      }
    }

    __syncthreads();  // drains h stores (vmcnt 0); all 4 waves done
    if (tid == 0)
      __hip_atomic_store(flg_g + t * 4 + slice, 1, __ATOMIC_RELAXED,
                         __HIP_MEMORY_SCOPE_AGENT);

    // ---- y stores from registers (after flag -> overlap next poll) ----
#pragma unroll
    for (int r = 0; r < 4; ++r) {
      const int m = quad * 4 + r;
      const int b = seqbase + m;
      size_t yb = ((size_t)b * 512 + t) * 1024 + colbase + l15;
      out[yb] = hv0[r];
      out[yb + 16] = hv1[r];
      out[yb + 512] = hv0[r];   // layer 1 == layer 0
      out[yb + 528] = hv1[r];
      if (t == 511) {
        size_t hoff = YSIZE + (size_t)b * 1024 + colbase + l15;
        out[hoff] = hv0[r];
        out[hoff + 16] = hv1[r];
        out[hoff + 512] = hv0[r];
        out[hoff + 528] = hv1[r];
      }
    }
  }
}

extern "C" void kernel_launch(void* const* d_in, const int* in_sizes, int n_in,
                              void* d_out, int out_size, void* d_ws, size_t ws_size,
                              hipStream_t stream) {
  (void)in_sizes; (void)n_in; (void)out_size; (void)ws_size;
  const float* x   = (const float*)d_in[0];
  const float* Wih = (const float*)d_in[1];
  const float* bih = (const float*)d_in[2];
  const float* Whh = (const float*)d_in[3];
  const float* bhh = (const float*)d_in[4];
  float* out = (float*)d_out;
  char* ws = (char*)d_ws;

  _Float16* xaH  = (_Float16*)(ws + XA_OFF);
  _Float16* WihH = (_Float16*)(ws + WIH_OFF);
  _Float16* WhhH = (_Float16*)(ws + WHH_OFF);
  float* hbuf    = (float*)(ws + HBUF_OFF);
  int* flgp      = (int*)(ws + FLG_OFF);

  prep_kernel<<<dim3(1024), dim3(256), 0, stream>>>(Wih, Whh, WihH, WhhH,
                                                    hbuf, flgp);
  gemm1_kernel<<<dim3(1024), dim3(256), 0, stream>>>(x, WihH, bih, bhh, xaH);
  rnn_kernel<<<dim3(16), dim3(256), 0, stream>>>(xaH, WhhH, hbuf, flgp, out);
}